// Round 4
// baseline (196.738 us; speedup 1.0000x reference)
//
#include <hip/hip_runtime.h>
#include <hip/hip_bf16.h>
#include <stdint.h>
#include <string.h>

typedef __attribute__((ext_vector_type(8))) short short8;   // 8 bf16 (4 VGPRs) MFMA operand
typedef __attribute__((ext_vector_type(4))) float floatx4;  // MFMA accumulator
typedef unsigned short u16;

#define NPTS 256   // points per group
#define DIM  256   // feature dim
#define BKF  32    // fused-kernel K-step (elems per slice)
#define NSL  (DIM / BKF)   // 8 K-slices

// HW packed fp32->bf16 RNE convert (v_cvt_pk_bf16_f32 on gfx950); also
// accumulates the squared sum of the ROUNDED values (consistent metric).
static __device__ __forceinline__ uint32_t cvtsq2(float a, float b, float& s) {
    __hip_bfloat162 h = __float22bfloat162_rn(float2{a, b});
    uint32_t d;
    memcpy(&d, &h, 4);
    const float lo = __builtin_bit_cast(float, d << 16);
    const float hi = __builtin_bit_cast(float, d & 0xFFFF0000u);
    s += lo * lo + hi * hi;
    return d;
}

// ---------------------------------------------------------------------------
// Fused: 3 blocks per group -> full 256x256 Gram each.
//   t=0: XY (w=+1)   t=1: XX (w=-0.5, A=B)   t=2: YY (w=-0.5, A=B)
// Conversion fp32->bf16 happens in-kernel, once per operand panel per block
// (2.5x less than the 128-tile scheme). Symmetric blocks stage ONE panel and
// feed it to both MFMA operands. No prepass, no global scratch.
// LDS: [row][32] bf16 rows (64B); 16B-chunk swizzle p = c ^ ((row>>1)&3)
// makes both ds_write_b128 (staging) and ds_read_b128 (fragments) 2-way
// (= free) on the 32 banks. Applied identically on write and read.
// ---------------------------------------------------------------------------
__global__ __launch_bounds__(512, 2)
void mmd_fused(const float* __restrict__ X, const float* __restrict__ Y,
               float* __restrict__ out, float scale, int G) {
    // ---- block -> (group, t) decode; 3 blocks of a group share an XCD ----
    int g, t;
    const int f = blockIdx.x;
    { const int xcd = f & 7, j = f >> 3; g = (j / 3) * 8 + xcd; t = j % 3; }
    const float w  = (t == 0) ? 1.0f : -0.5f;
    const bool sym = (t != 0);
    const float* Pf = (t == 2) ? Y : X;
    const float* Qf = (t == 1) ? X : Y;
    const size_t base = (size_t)g * NPTS * DIM;

    __shared__ __align__(16) u16 As[2][NPTS * BKF];   // 2 x 16 KB
    __shared__ __align__(16) u16 Bs[2][NPTS * BKF];   // 2 x 16 KB
    __shared__ float rnormS[NPTS];
    __shared__ float cnormS[NPTS];
    __shared__ float wpart[8];

    const int tid  = threadIdx.x;          // 0..511
    const int lane = tid & 63;
    const int wv   = tid >> 6;             // 0..7
    const int quad = lane >> 4;
    const int l15  = lane & 15;
    const int wr   = (wv & 3) * 64;        // wave's 64-row stripe
    const int wc   = (wv >> 2) * 128;      // wave's 128-col stripe
    // fragment read: row = 16m + l15, chunk = quad; phys chunk = quad^((row>>1)&3)
    const int rsw  = (quad ^ ((l15 >> 1) & 3)) * 8;   // swizzled elem offset

    // ---- staging geometry: thread t covers row tid>>1, 16 fp32 cols ----
    const int srow = tid >> 1;
    const int scol = (tid & 1) * 16;
    const float* gP = Pf + base + (size_t)srow * DIM + scol;
    const float* gQ = Qf + base + (size_t)srow * DIM + scol;
    const int c0   = (tid & 1) * 2;                   // logical 16B chunk
    const int sswz = (srow >> 1) & 3;
    const int wo0  = srow * BKF + ((c0    ) ^ sswz) * 8;
    const int wo1  = srow * BKF + ((c0 + 1) ^ sswz) * 8;

    floatx4 acc[4][8];
    #pragma unroll
    for (int i = 0; i < 4; ++i)
        #pragma unroll
        for (int j = 0; j < 8; ++j) acc[i][j] = (floatx4)0.0f;

    float sqp = 0.0f, sqq = 0.0f;          // row-norm partials (rounded vals)
    float4 ra[4], rb[4];

    // ---- prologue: slice 0 -> LDS[0]; start loading slice 1 ----
    #pragma unroll
    for (int q = 0; q < 4; ++q) ra[q] = *(const float4*)(gP + q * 4);
    if (!sym) {
        #pragma unroll
        for (int q = 0; q < 4; ++q) rb[q] = *(const float4*)(gQ + q * 4);
    }
    {
        uint4 u0, u1;
        u0.x = cvtsq2(ra[0].x, ra[0].y, sqp); u0.y = cvtsq2(ra[0].z, ra[0].w, sqp);
        u0.z = cvtsq2(ra[1].x, ra[1].y, sqp); u0.w = cvtsq2(ra[1].z, ra[1].w, sqp);
        u1.x = cvtsq2(ra[2].x, ra[2].y, sqp); u1.y = cvtsq2(ra[2].z, ra[2].w, sqp);
        u1.z = cvtsq2(ra[3].x, ra[3].y, sqp); u1.w = cvtsq2(ra[3].z, ra[3].w, sqp);
        *(uint4*)&As[0][wo0] = u0; *(uint4*)&As[0][wo1] = u1;
        if (!sym) {
            uint4 v0, v1;
            v0.x = cvtsq2(rb[0].x, rb[0].y, sqq); v0.y = cvtsq2(rb[0].z, rb[0].w, sqq);
            v0.z = cvtsq2(rb[1].x, rb[1].y, sqq); v0.w = cvtsq2(rb[1].z, rb[1].w, sqq);
            v1.x = cvtsq2(rb[2].x, rb[2].y, sqq); v1.y = cvtsq2(rb[2].z, rb[2].w, sqq);
            v1.z = cvtsq2(rb[3].x, rb[3].y, sqq); v1.w = cvtsq2(rb[3].z, rb[3].w, sqq);
            *(uint4*)&Bs[0][wo0] = v0; *(uint4*)&Bs[0][wo1] = v1;
        }
    }
    #pragma unroll
    for (int q = 0; q < 4; ++q) ra[q] = *(const float4*)(gP + BKF + q * 4);
    if (!sym) {
        #pragma unroll
        for (int q = 0; q < 4; ++q) rb[q] = *(const float4*)(gQ + BKF + q * 4);
    }

    // ---- main pipeline: 1 barrier/iter, write-ahead-1, load-ahead-2 ----
    #pragma unroll
    for (int it = 0; it < NSL; ++it) {
        const int b = it & 1;
        __syncthreads();                    // LDS[b] (written last iter) visible

        if (it < NSL - 1) {                 // write slice it+1 into LDS[b^1]
            uint4 u0, u1;
            u0.x = cvtsq2(ra[0].x, ra[0].y, sqp); u0.y = cvtsq2(ra[0].z, ra[0].w, sqp);
            u0.z = cvtsq2(ra[1].x, ra[1].y, sqp); u0.w = cvtsq2(ra[1].z, ra[1].w, sqp);
            u1.x = cvtsq2(ra[2].x, ra[2].y, sqp); u1.y = cvtsq2(ra[2].z, ra[2].w, sqp);
            u1.z = cvtsq2(ra[3].x, ra[3].y, sqp); u1.w = cvtsq2(ra[3].z, ra[3].w, sqp);
            *(uint4*)&As[b ^ 1][wo0] = u0; *(uint4*)&As[b ^ 1][wo1] = u1;
            if (!sym) {
                uint4 v0, v1;
                v0.x = cvtsq2(rb[0].x, rb[0].y, sqq); v0.y = cvtsq2(rb[0].z, rb[0].w, sqq);
                v0.z = cvtsq2(rb[1].x, rb[1].y, sqq); v0.w = cvtsq2(rb[1].z, rb[1].w, sqq);
                v1.x = cvtsq2(rb[2].x, rb[2].y, sqq); v1.y = cvtsq2(rb[2].z, rb[2].w, sqq);
                v1.z = cvtsq2(rb[3].x, rb[3].y, sqq); v1.w = cvtsq2(rb[3].z, rb[3].w, sqq);
                *(uint4*)&Bs[b ^ 1][wo0] = v0; *(uint4*)&Bs[b ^ 1][wo1] = v1;
            }
        }
        if (it < NSL - 2) {                 // start loading slice it+2
            const int k0 = (it + 2) * BKF;
            #pragma unroll
            for (int q = 0; q < 4; ++q) ra[q] = *(const float4*)(gP + k0 + q * 4);
            if (!sym) {
                #pragma unroll
                for (int q = 0; q < 4; ++q) rb[q] = *(const float4*)(gQ + k0 + q * 4);
            }
        }

        // consume slice it from LDS[b]
        const u16* ab = As[b];
        const u16* bb = sym ? As[b] : Bs[b];
        short8 af[4], bfv[8];
        #pragma unroll
        for (int mi = 0; mi < 4; ++mi)
            af[mi] = *(const short8*)&ab[(wr + mi * 16 + l15) * BKF + rsw];
        #pragma unroll
        for (int ni = 0; ni < 8; ++ni)
            bfv[ni] = *(const short8*)&bb[(wc + ni * 16 + l15) * BKF + rsw];
        #pragma unroll
        for (int mi = 0; mi < 4; ++mi)
            #pragma unroll
            for (int ni = 0; ni < 8; ++ni)
                acc[mi][ni] = __builtin_amdgcn_mfma_f32_16x16x32_bf16(
                    af[mi], bfv[ni], acc[mi][ni], 0, 0, 0);
    }

    // ---- assemble row/col norms (2 staging threads per row) ----
    sqp += __shfl_xor(sqp, 1);
    sqq += __shfl_xor(sqq, 1);
    if ((tid & 1) == 0) {
        rnormS[srow] = sqp;
        cnormS[srow] = sym ? sqp : sqq;
    }
    __syncthreads();

    // ---- fused epilogue: d = sqrt(max(x2_i + y2_j - 2 S_ij, 0)) ----
    // C/D layout: col = lane&15, row = (lane>>4)*4 + reg.
    float lsum = 0.0f;
    #pragma unroll
    for (int mi = 0; mi < 4; ++mi) {
        #pragma unroll
        for (int i = 0; i < 4; ++i) {
            const int r = wr + mi * 16 + quad * 4 + i;
            const float rv = rnormS[r];
            #pragma unroll
            for (int ni = 0; ni < 8; ++ni) {
                const int c = wc + ni * 16 + l15;
                float d2 = rv + cnormS[c] - 2.0f * acc[mi][ni][i];
                float s = sqrtf(fmaxf(d2, 0.0f));
                if (sym && (r == c)) s = 0.0f;
                lsum += s;
            }
        }
    }
    #pragma unroll
    for (int off = 32; off; off >>= 1) lsum += __shfl_down(lsum, off);
    if (lane == 0) wpart[wv] = lsum;
    __syncthreads();
    if (tid == 0) {
        float bs = 0.0f;
        #pragma unroll
        for (int i = 0; i < 8; ++i) bs += wpart[i];
        atomicAdd(out, bs * (w * scale));
    }
}

// ---------------------------------------------------------------------------
// Fallback (round-0 verified kernel): 128-tile fused conversion + GEMM.
// Used only if G isn't a multiple of 8.
// ---------------------------------------------------------------------------
#define TILE 128
#define BK   32
#define NIT  (DIM / BK)
#define LDSS 40

__global__ __launch_bounds__(512, 4)
void mmd_pipe(const float* __restrict__ X, const float* __restrict__ Y,
              float* __restrict__ out, float scale, int G) {
    int g, t;
    const int f = blockIdx.x;
    if ((G & 7) == 0) { const int xcd = f & 7, j = f >> 3; g = (j / 10) * 8 + xcd; t = j % 10; }
    else              { g = f / 10; t = f % 10; }

    int ptype, ti, tj; float w;
    if (t < 4)      { ptype = 0; ti = t >> 1; tj = t & 1; w = 1.0f; }
    else if (t < 7) { int u = t - 4; ptype = 1; ti = (u == 2); tj = (u >= 1); w = (u == 1) ? -1.0f : -0.5f; }
    else            { int u = t - 7; ptype = 2; ti = (u == 2); tj = (u >= 1); w = (u == 1) ? -1.0f : -0.5f; }

    const float *Pf, *Qf;
    if (ptype == 0)      { Pf = X; Qf = Y; }
    else if (ptype == 1) { Pf = X; Qf = X; }
    else                 { Pf = Y; Qf = Y; }
    const bool symdiag = (ptype != 0) && (ti == tj);

    const size_t prow0 = (size_t)g * NPTS + (size_t)ti * TILE;
    const size_t qrow0 = (size_t)g * NPTS + (size_t)tj * TILE;

    __shared__ __align__(16) uint16_t As[2][TILE * LDSS];
    __shared__ __align__(16) uint16_t Bs[2][TILE * LDSS];
    __shared__ float rnorm[TILE];
    __shared__ float cnorm[TILE];
    __shared__ float wpart[8];

    const int tid  = threadIdx.x;
    const int lane = tid & 63;
    const int wv   = tid >> 6;
    const int quad = lane >> 4;
    const int l15  = lane & 15;
    const int rowbase = (wv & 3) * 32;
    const int colbase = (wv >> 2) * 64;

    const int prow = tid >> 2;
    const int pcol = (tid & 3) * 8;
    const float* gA = Pf + (prow0 + prow) * DIM + pcol;
    const float* gB = Qf + (qrow0 + prow) * DIM + pcol;
    const int woff = prow * LDSS + pcol;

    floatx4 acc[2][4];
    #pragma unroll
    for (int i = 0; i < 2; ++i)
        #pragma unroll
        for (int j = 0; j < 4; ++j) acc[i][j] = (floatx4)0.0f;

    float sqp = 0.0f, sqq = 0.0f;

    float4 ra0 = *(const float4*)(gA);
    float4 ra1 = *(const float4*)(gA + 4);
    float4 rb0 = *(const float4*)(gB);
    float4 rb1 = *(const float4*)(gB + 4);
    {
        uint4 pa, pb;
        pa.x = cvtsq2(ra0.x, ra0.y, sqp); pa.y = cvtsq2(ra0.z, ra0.w, sqp);
        pa.z = cvtsq2(ra1.x, ra1.y, sqp); pa.w = cvtsq2(ra1.z, ra1.w, sqp);
        pb.x = cvtsq2(rb0.x, rb0.y, sqq); pb.y = cvtsq2(rb0.z, rb0.w, sqq);
        pb.z = cvtsq2(rb1.x, rb1.y, sqq); pb.w = cvtsq2(rb1.z, rb1.w, sqq);
        *(uint4*)&As[0][woff] = pa;
        *(uint4*)&Bs[0][woff] = pb;
    }
    ra0 = *(const float4*)(gA + BK);
    ra1 = *(const float4*)(gA + BK + 4);
    rb0 = *(const float4*)(gB + BK);
    rb1 = *(const float4*)(gB + BK + 4);

    #pragma unroll
    for (int it = 0; it < NIT; ++it) {
        const int b = it & 1;
        __syncthreads();

        if (it < NIT - 1) {
            uint4 pa, pb;
            pa.x = cvtsq2(ra0.x, ra0.y, sqp); pa.y = cvtsq2(ra0.z, ra0.w, sqp);
            pa.z = cvtsq2(ra1.x, ra1.y, sqp); pa.w = cvtsq2(ra1.z, ra1.w, sqp);
            pb.x = cvtsq2(rb0.x, rb0.y, sqq); pb.y = cvtsq2(rb0.z, rb0.w, sqq);
            pb.z = cvtsq2(rb1.x, rb1.y, sqq); pb.w = cvtsq2(rb1.z, rb1.w, sqq);
            *(uint4*)&As[b ^ 1][woff] = pa;
            *(uint4*)&Bs[b ^ 1][woff] = pb;
        }
        if (it < NIT - 2) {
            const int k0 = (it + 2) * BK;
            ra0 = *(const float4*)(gA + k0);
            ra1 = *(const float4*)(gA + k0 + 4);
            rb0 = *(const float4*)(gB + k0);
            rb1 = *(const float4*)(gB + k0 + 4);
        }

        short8 af[2], bfr[4];
        #pragma unroll
        for (int mi = 0; mi < 2; ++mi)
            af[mi] = *(const short8*)&As[b][(rowbase + mi * 16 + l15) * LDSS + quad * 8];
        #pragma unroll
        for (int ni = 0; ni < 4; ++ni)
            bfr[ni] = *(const short8*)&Bs[b][(colbase + ni * 16 + l15) * LDSS + quad * 8];
        #pragma unroll
        for (int mi = 0; mi < 2; ++mi)
            #pragma unroll
            for (int ni = 0; ni < 4; ++ni)
                acc[mi][ni] = __builtin_amdgcn_mfma_f32_16x16x32_bf16(
                    af[mi], bfr[ni], acc[mi][ni], 0, 0, 0);
    }

    sqp += __shfl_xor(sqp, 1); sqp += __shfl_xor(sqp, 2);
    sqq += __shfl_xor(sqq, 1); sqq += __shfl_xor(sqq, 2);
    if ((tid & 3) == 0) { rnorm[prow] = sqp; cnorm[prow] = sqq; }
    __syncthreads();

    float lsum = 0.0f;
    #pragma unroll
    for (int mi = 0; mi < 2; ++mi) {
        #pragma unroll
        for (int i = 0; i < 4; ++i) {
            const int r = rowbase + mi * 16 + quad * 4 + i;
            const float rv = rnorm[r];
            #pragma unroll
            for (int ni = 0; ni < 4; ++ni) {
                const int c = colbase + ni * 16 + l15;
                float d2 = rv + cnorm[c] - 2.0f * acc[mi][ni][i];
                float s = sqrtf(fmaxf(d2, 0.0f));
                if (symdiag && (r == c)) s = 0.0f;
                lsum += s;
            }
        }
    }
    #pragma unroll
    for (int off = 32; off; off >>= 1) lsum += __shfl_down(lsum, off);
    if (lane == 0) wpart[wv] = lsum;
    __syncthreads();
    if (tid == 0) {
        float bs = 0.0f;
        #pragma unroll
        for (int i = 0; i < 8; ++i) bs += wpart[i];
        atomicAdd(out, bs * (w * scale));
    }
}

// ---------------------------------------------------------------------------
extern "C" void kernel_launch(void* const* d_in, const int* in_sizes, int n_in,
                              void* d_out, int out_size, void* d_ws, size_t ws_size,
                              hipStream_t stream) {
    const float* X = (const float*)d_in[0];
    const float* Y = (const float*)d_in[1];
    const int total_elems = in_sizes[0];          // G*NPTS*DIM
    const int G = total_elems / (NPTS * DIM);     // 128

    float* out = (float*)d_out;
    hipMemsetAsync(out, 0, sizeof(float) * out_size, stream);

    const float scale = 1.0f / ((float)NPTS * (float)NPTS * (float)G);

    if ((G & 7) == 0) {
        mmd_fused<<<3 * G, 512, 0, stream>>>(X, Y, out, scale, G);
    } else {
        mmd_pipe<<<10 * G, 512, 0, stream>>>(X, Y, out, scale, G);
    }
}

// Round 5
// 181.524 us; speedup vs baseline: 1.0838x; 1.0838x over previous
//
#include <hip/hip_runtime.h>
#include <hip/hip_bf16.h>
#include <stdint.h>
#include <string.h>

typedef __attribute__((ext_vector_type(8))) short short8;   // 8 bf16 (4 VGPRs) MFMA operand
typedef __attribute__((ext_vector_type(4))) float floatx4;  // MFMA accumulator

#define NPTS 256   // points per group
#define DIM  256   // feature dim
#define TILE 128   // output tile per block
#define BK   32    // K-step (elems per slice; one 16x16x32 MFMA K)
#define NIT  (DIM / BK)          // 8 K-iterations

// HW packed fp32->bf16 RNE convert (v_cvt_pk_bf16_f32 on gfx950); also
// accumulates the squared sum of the ROUNDED values (consistent metric).
static __device__ __forceinline__ uint32_t cvtsq2(float a, float b, float& s) {
    __hip_bfloat162 h = __float22bfloat162_rn(float2{a, b});
    uint32_t d;
    memcpy(&d, &h, 4);
    const float lo = __builtin_bit_cast(float, d << 16);
    const float hi = __builtin_bit_cast(float, d & 0xFFFF0000u);
    s += lo * lo + hi * hi;
    return d;
}

// ---------------------------------------------------------------------------
// grid = 10*G linear blocks, XCD-swizzled so all 10 tiles of a group share an
// XCD (L2 reuse). t 0..3 = XY (w=+1), 4..6 = XX upper-tri (w=-0.5/-1/-0.5,
// off-diag tile double-counted via w), 7..9 = YY upper-tri.
//
// LDS layout (round-4-verified, SQ_LDS_BANK_CONFLICT measured 0):
//   [row][32] bf16 rows (64 B = 4 16B-chunks), physical chunk
//   p = c ^ ((row>>1)&3), applied identically on ds_write (staging) and
//   ds_read_b128 (fragments). Every 8-lane beat covers all 8 bank groups.
// LDS total 33 KB (vs round-0's 42.5 KB) -> up to 4 blocks/CU.
// symdiag blocks stage/convert ONE panel only (B = A).
// ---------------------------------------------------------------------------
__global__ __launch_bounds__(512, 4)
void mmd_pipe(const float* __restrict__ X, const float* __restrict__ Y,
              float* __restrict__ out, float scale, int G) {
    // ---- block -> (group, tile) decode with XCD swizzle ----
    int g, t;
    const int f = blockIdx.x;
    if ((G & 7) == 0) { const int xcd = f & 7, j = f >> 3; g = (j / 10) * 8 + xcd; t = j % 10; }
    else              { g = f / 10; t = f % 10; }

    int ptype, ti, tj; float w;
    if (t < 4)      { ptype = 0; ti = t >> 1; tj = t & 1; w = 1.0f; }
    else if (t < 7) { int u = t - 4; ptype = 1; ti = (u == 2); tj = (u >= 1); w = (u == 1) ? -1.0f : -0.5f; }
    else            { int u = t - 7; ptype = 2; ti = (u == 2); tj = (u >= 1); w = (u == 1) ? -1.0f : -0.5f; }

    const float *Pf, *Qf;
    if (ptype == 0)      { Pf = X; Qf = Y; }
    else if (ptype == 1) { Pf = X; Qf = X; }
    else                 { Pf = Y; Qf = Y; }
    const bool symdiag = (ptype != 0) && (ti == tj);   // A panel == B panel

    const size_t prow0 = (size_t)g * NPTS + (size_t)ti * TILE;
    const size_t qrow0 = (size_t)g * NPTS + (size_t)tj * TILE;

    __shared__ __align__(16) uint16_t As[2][TILE * BK];  // 2 x 8 KB
    __shared__ __align__(16) uint16_t Bs[2][TILE * BK];  // 2 x 8 KB
    __shared__ float rnorm[TILE];
    __shared__ float cnorm[TILE];
    __shared__ float wpart[8];

    const int tid  = threadIdx.x;          // 0..511
    const int lane = tid & 63;
    const int wv   = tid >> 6;             // 0..7
    const int quad = lane >> 4;
    const int l15  = lane & 15;
    const int rowbase = (wv & 3) * 32;     // wave's 32-row stripe
    const int colbase = (wv >> 2) * 64;    // wave's 64-col stripe
    // fragment read: row = base + l15 (base % 16 == 0), logical chunk = quad,
    // physical chunk = quad ^ ((row>>1)&3) = quad ^ ((l15>>1)&3)
    const int rsw = (quad ^ ((l15 >> 1) & 3)) * 8;   // swizzled elem offset

    // ---- producer geometry: thread covers row tid>>2, 16B chunk tid&3 ----
    const int prow = tid >> 2;             // 0..127
    const int pchk = tid & 3;              // logical chunk in row
    const float* gA = Pf + (prow0 + prow) * DIM + pchk * 8;
    const float* gB = Qf + (qrow0 + prow) * DIM + pchk * 8;
    const int woff = prow * BK + ((pchk ^ ((prow >> 1) & 3)) * 8);  // swizzled

    floatx4 acc[2][4];
    #pragma unroll
    for (int i = 0; i < 2; ++i)
        #pragma unroll
        for (int j = 0; j < 4; ++j) acc[i][j] = (floatx4)0.0f;

    float sqp = 0.0f, sqq = 0.0f;          // this thread's partial row norms

    // ---- prologue: slice 0 -> LDS[0]; start loading slice 1 ----
    float4 ra0 = *(const float4*)(gA);
    float4 ra1 = *(const float4*)(gA + 4);
    float4 rb0, rb1;
    if (!symdiag) { rb0 = *(const float4*)(gB); rb1 = *(const float4*)(gB + 4); }
    {
        uint4 pa;
        pa.x = cvtsq2(ra0.x, ra0.y, sqp); pa.y = cvtsq2(ra0.z, ra0.w, sqp);
        pa.z = cvtsq2(ra1.x, ra1.y, sqp); pa.w = cvtsq2(ra1.z, ra1.w, sqp);
        *(uint4*)&As[0][woff] = pa;
        if (!symdiag) {
            uint4 pb;
            pb.x = cvtsq2(rb0.x, rb0.y, sqq); pb.y = cvtsq2(rb0.z, rb0.w, sqq);
            pb.z = cvtsq2(rb1.x, rb1.y, sqq); pb.w = cvtsq2(rb1.z, rb1.w, sqq);
            *(uint4*)&Bs[0][woff] = pb;
        }
    }
    ra0 = *(const float4*)(gA + BK);
    ra1 = *(const float4*)(gA + BK + 4);
    if (!symdiag) {
        rb0 = *(const float4*)(gB + BK);
        rb1 = *(const float4*)(gB + BK + 4);
    }

    // ---- main pipeline: 1 barrier/iter, write-ahead-1, load-ahead-2 ----
    #pragma unroll
    for (int it = 0; it < NIT; ++it) {
        const int b = it & 1;
        __syncthreads();                    // LDS[b] (written last iter) visible

        if (it < NIT - 1) {                 // write slice it+1 into LDS[b^1]
            uint4 pa;
            pa.x = cvtsq2(ra0.x, ra0.y, sqp); pa.y = cvtsq2(ra0.z, ra0.w, sqp);
            pa.z = cvtsq2(ra1.x, ra1.y, sqp); pa.w = cvtsq2(ra1.z, ra1.w, sqp);
            *(uint4*)&As[b ^ 1][woff] = pa;
            if (!symdiag) {
                uint4 pb;
                pb.x = cvtsq2(rb0.x, rb0.y, sqq); pb.y = cvtsq2(rb0.z, rb0.w, sqq);
                pb.z = cvtsq2(rb1.x, rb1.y, sqq); pb.w = cvtsq2(rb1.z, rb1.w, sqq);
                *(uint4*)&Bs[b ^ 1][woff] = pb;
            }
        }
        if (it < NIT - 2) {                 // start loading slice it+2
            const int k0 = (it + 2) * BK;
            ra0 = *(const float4*)(gA + k0);
            ra1 = *(const float4*)(gA + k0 + 4);
            if (!symdiag) {
                rb0 = *(const float4*)(gB + k0);
                rb1 = *(const float4*)(gB + k0 + 4);
            }
        }

        // consume slice it from LDS[b]
        const uint16_t* ab = As[b];
        const uint16_t* bb = symdiag ? As[b] : Bs[b];
        short8 af[2], bfr[4];
        #pragma unroll
        for (int mi = 0; mi < 2; ++mi)
            af[mi] = *(const short8*)&ab[(rowbase + mi * 16 + l15) * BK + rsw];
        #pragma unroll
        for (int ni = 0; ni < 4; ++ni)
            bfr[ni] = *(const short8*)&bb[(colbase + ni * 16 + l15) * BK + rsw];
        #pragma unroll
        for (int mi = 0; mi < 2; ++mi)
            #pragma unroll
            for (int ni = 0; ni < 4; ++ni)
                acc[mi][ni] = __builtin_amdgcn_mfma_f32_16x16x32_bf16(
                    af[mi], bfr[ni], acc[mi][ni], 0, 0, 0);
    }

    // ---- assemble row/col norms: reduce over the 4 staging threads per row
    sqp += __shfl_xor(sqp, 1); sqp += __shfl_xor(sqp, 2);
    if (!symdiag) { sqq += __shfl_xor(sqq, 1); sqq += __shfl_xor(sqq, 2); }
    if ((tid & 3) == 0) {
        rnorm[prow] = sqp;
        cnorm[prow] = symdiag ? sqp : sqq;
    }
    __syncthreads();

    // ---- fused epilogue: d = sqrt(max(x2_i + y2_j - 2 S_ij, 0)) ----
    // C/D layout: col = lane&15, row = (lane>>4)*4 + reg.
    float lsum = 0.0f;
    #pragma unroll
    for (int mi = 0; mi < 2; ++mi) {
        #pragma unroll
        for (int i = 0; i < 4; ++i) {
            const int r = rowbase + mi * 16 + quad * 4 + i;
            const float rv = rnorm[r];
            #pragma unroll
            for (int ni = 0; ni < 4; ++ni) {
                const int c = colbase + ni * 16 + l15;
                float d2 = rv + cnorm[c] - 2.0f * acc[mi][ni][i];
                float s = sqrtf(fmaxf(d2, 0.0f));
                if (symdiag && (r == c)) s = 0.0f;
                lsum += s;
            }
        }
    }
    #pragma unroll
    for (int off = 32; off; off >>= 1) lsum += __shfl_down(lsum, off);
    if (lane == 0) wpart[wv] = lsum;
    __syncthreads();
    if (tid == 0) {
        float bs = 0.0f;
        #pragma unroll
        for (int i = 0; i < 8; ++i) bs += wpart[i];
        atomicAdd(out, bs * (w * scale));
    }
}

// ---------------------------------------------------------------------------
extern "C" void kernel_launch(void* const* d_in, const int* in_sizes, int n_in,
                              void* d_out, int out_size, void* d_ws, size_t ws_size,
                              hipStream_t stream) {
    const float* X = (const float*)d_in[0];
    const float* Y = (const float*)d_in[1];
    const int total_elems = in_sizes[0];          // G*NPTS*DIM
    const int G = total_elems / (NPTS * DIM);     // 128

    float* out = (float*)d_out;
    hipMemsetAsync(out, 0, sizeof(float) * out_size, stream);

    const float scale = 1.0f / ((float)NPTS * (float)NPTS * (float)G);
    mmd_pipe<<<10 * G, 512, 0, stream>>>(X, Y, out, scale, G);
}

// Round 6
// 124.578 us; speedup vs baseline: 1.5792x; 1.4571x over previous
//
#include <hip/hip_runtime.h>
#include <hip/hip_bf16.h>
#include <stdint.h>
#include <string.h>

typedef __attribute__((ext_vector_type(8))) short short8;   // 8 bf16 (4 VGPRs) MFMA operand
typedef __attribute__((ext_vector_type(4))) float floatx4;  // MFMA accumulator

#define NPTS 256   // points per group
#define DIM  256   // feature dim
#define TILE 128   // output tile per block
#define BK   32    // K-step
#define NIT  (DIM / BK)          // 8 K-iterations

// HW packed fp32->bf16 RNE convert (v_cvt_pk_bf16_f32 on gfx950); also
// accumulates the squared sum of the ROUNDED values (consistent metric).
static __device__ __forceinline__ uint32_t cvtsq2(float a, float b, float& s) {
    __hip_bfloat162 h = __float22bfloat162_rn(float2{a, b});
    uint32_t d;
    memcpy(&d, &h, 4);
    const float lo = __builtin_bit_cast(float, d << 16);
    const float hi = __builtin_bit_cast(float, d & 0xFFFF0000u);
    s += lo * lo + hi * hi;
    return d;
}

// ---------------------------------------------------------------------------
// grid = 10*G linear blocks, XCD-swizzled so all 10 tiles of a group share an
// XCD (L2 reuse). t 0..3 = XY (w=+1), 4..6 = XX upper-tri (w=-0.5/-1/-0.5,
// off-diag tile double-counted via w), 7..9 = YY upper-tri.
//
// This is the round-0 kernel (44 VGPR, verified 52us) with ONE change:
// LDS layout [row][32] linear, 16B-chunk swizzle p = c ^ ((row>>1)&3) applied
// identically on ds_write (staging) and ds_read_b128 (fragments).
// HW-verified: SQ_LDS_BANK_CONFLICT == 0 (rounds 4 & 5) vs 3.28M with the
// padded-stride layout. LDS 42.5 -> 33.8 KB (4 blocks/CU now fit).
// Staging is UNCONDITIONAL for both panels — round-5's symdiag-conditional
// staging pushed VGPRs past the 64 cliff and spilled 138 MB to scratch.
// ---------------------------------------------------------------------------
__global__ __launch_bounds__(512, 4)
void mmd_pipe(const float* __restrict__ X, const float* __restrict__ Y,
              float* __restrict__ out, float scale, int G) {
    // ---- block -> (group, tile) decode with XCD swizzle ----
    int g, t;
    const int f = blockIdx.x;
    if ((G & 7) == 0) { const int xcd = f & 7, j = f >> 3; g = (j / 10) * 8 + xcd; t = j % 10; }
    else              { g = f / 10; t = f % 10; }

    int ptype, ti, tj; float w;
    if (t < 4)      { ptype = 0; ti = t >> 1; tj = t & 1; w = 1.0f; }
    else if (t < 7) { int u = t - 4; ptype = 1; ti = (u == 2); tj = (u >= 1); w = (u == 1) ? -1.0f : -0.5f; }
    else            { int u = t - 7; ptype = 2; ti = (u == 2); tj = (u >= 1); w = (u == 1) ? -1.0f : -0.5f; }

    const float *Pf, *Qf;
    if (ptype == 0)      { Pf = X; Qf = Y; }
    else if (ptype == 1) { Pf = X; Qf = X; }
    else                 { Pf = Y; Qf = Y; }
    const bool symdiag = (ptype != 0) && (ti == tj);

    const size_t prow0 = (size_t)g * NPTS + (size_t)ti * TILE;
    const size_t qrow0 = (size_t)g * NPTS + (size_t)tj * TILE;

    __shared__ __align__(16) uint16_t As[2][TILE * BK];  // 2 x 8 KB
    __shared__ __align__(16) uint16_t Bs[2][TILE * BK];  // 2 x 8 KB
    __shared__ float rnorm[TILE];
    __shared__ float cnorm[TILE];
    __shared__ float wpart[8];

    const int tid  = threadIdx.x;          // 0..511
    const int lane = tid & 63;
    const int wv   = tid >> 6;             // 0..7
    const int quad = lane >> 4;
    const int l15  = lane & 15;
    const int rowbase = (wv & 3) * 32;     // wave's 32-row stripe
    const int colbase = (wv >> 2) * 64;    // wave's 64-col stripe
    // fragment read: row = base16 + l15 -> (row>>1)&3 == (l15>>1)&3
    const int rsw = (quad ^ ((l15 >> 1) & 3)) * 8;   // swizzled elem offset

    // ---- producer geometry: thread covers row tid>>2, 16B chunk tid&3 ----
    const int prow = tid >> 2;
    const int pchk = tid & 3;
    const float* gA = Pf + (prow0 + prow) * DIM + pchk * 8;
    const float* gB = Qf + (qrow0 + prow) * DIM + pchk * 8;
    const int woff = prow * BK + ((pchk ^ ((prow >> 1) & 3)) * 8);  // swizzled

    floatx4 acc[2][4];
    #pragma unroll
    for (int i = 0; i < 2; ++i)
        #pragma unroll
        for (int j = 0; j < 4; ++j) acc[i][j] = (floatx4)0.0f;

    float sqp = 0.0f, sqq = 0.0f;          // this thread's partial row norms

    // ---- prologue: slice 0 -> LDS[0]; start loading slice 1 ----
    float4 ra0 = *(const float4*)(gA);
    float4 ra1 = *(const float4*)(gA + 4);
    float4 rb0 = *(const float4*)(gB);
    float4 rb1 = *(const float4*)(gB + 4);
    {
        uint4 pa, pb;
        pa.x = cvtsq2(ra0.x, ra0.y, sqp); pa.y = cvtsq2(ra0.z, ra0.w, sqp);
        pa.z = cvtsq2(ra1.x, ra1.y, sqp); pa.w = cvtsq2(ra1.z, ra1.w, sqp);
        pb.x = cvtsq2(rb0.x, rb0.y, sqq); pb.y = cvtsq2(rb0.z, rb0.w, sqq);
        pb.z = cvtsq2(rb1.x, rb1.y, sqq); pb.w = cvtsq2(rb1.z, rb1.w, sqq);
        *(uint4*)&As[0][woff] = pa;
        *(uint4*)&Bs[0][woff] = pb;
    }
    ra0 = *(const float4*)(gA + BK);
    ra1 = *(const float4*)(gA + BK + 4);
    rb0 = *(const float4*)(gB + BK);
    rb1 = *(const float4*)(gB + BK + 4);

    // ---- main pipeline: 1 barrier per iteration, write-ahead-1, load-ahead-2
    #pragma unroll
    for (int it = 0; it < NIT; ++it) {
        const int b = it & 1;
        __syncthreads();                    // LDS[b] (written last iter) visible

        if (it < NIT - 1) {                 // write slice it+1 into LDS[b^1]
            uint4 pa, pb;
            pa.x = cvtsq2(ra0.x, ra0.y, sqp); pa.y = cvtsq2(ra0.z, ra0.w, sqp);
            pa.z = cvtsq2(ra1.x, ra1.y, sqp); pa.w = cvtsq2(ra1.z, ra1.w, sqp);
            pb.x = cvtsq2(rb0.x, rb0.y, sqq); pb.y = cvtsq2(rb0.z, rb0.w, sqq);
            pb.z = cvtsq2(rb1.x, rb1.y, sqq); pb.w = cvtsq2(rb1.z, rb1.w, sqq);
            *(uint4*)&As[b ^ 1][woff] = pa;
            *(uint4*)&Bs[b ^ 1][woff] = pb;
        }
        if (it < NIT - 2) {                 // start loading slice it+2
            const int k0 = (it + 2) * BK;
            ra0 = *(const float4*)(gA + k0);
            ra1 = *(const float4*)(gA + k0 + 4);
            rb0 = *(const float4*)(gB + k0);
            rb1 = *(const float4*)(gB + k0 + 4);
        }

        // consume slice it from LDS[b]
        short8 af[2], bfr[4];
        #pragma unroll
        for (int mi = 0; mi < 2; ++mi)
            af[mi] = *(const short8*)&As[b][(rowbase + mi * 16 + l15) * BK + rsw];
        #pragma unroll
        for (int ni = 0; ni < 4; ++ni)
            bfr[ni] = *(const short8*)&Bs[b][(colbase + ni * 16 + l15) * BK + rsw];
        #pragma unroll
        for (int mi = 0; mi < 2; ++mi)
            #pragma unroll
            for (int ni = 0; ni < 4; ++ni)
                acc[mi][ni] = __builtin_amdgcn_mfma_f32_16x16x32_bf16(
                    af[mi], bfr[ni], acc[mi][ni], 0, 0, 0);
    }

    // ---- assemble row/col norms: reduce over the 4 staging threads per row
    sqp += __shfl_xor(sqp, 1); sqp += __shfl_xor(sqp, 2);
    sqq += __shfl_xor(sqq, 1); sqq += __shfl_xor(sqq, 2);
    if ((tid & 3) == 0) { rnorm[prow] = sqp; cnorm[prow] = sqq; }
    __syncthreads();

    // ---- fused epilogue: d = sqrt(max(x2_i + y2_j - 2 S_ij, 0)) ----
    // C/D layout: col = lane&15, row = (lane>>4)*4 + reg.
    float lsum = 0.0f;
    #pragma unroll
    for (int mi = 0; mi < 2; ++mi) {
        #pragma unroll
        for (int i = 0; i < 4; ++i) {
            const int r = rowbase + mi * 16 + quad * 4 + i;
            const float rv = rnorm[r];
            #pragma unroll
            for (int ni = 0; ni < 4; ++ni) {
                const int c = colbase + ni * 16 + l15;
                float d2 = rv + cnorm[c] - 2.0f * acc[mi][ni][i];
                float s = sqrtf(fmaxf(d2, 0.0f));
                if (symdiag && (r == c)) s = 0.0f;
                lsum += s;
            }
        }
    }
    #pragma unroll
    for (int off = 32; off; off >>= 1) lsum += __shfl_down(lsum, off);
    if (lane == 0) wpart[wv] = lsum;
    __syncthreads();
    if (tid == 0) {
        float bs = 0.0f;
        #pragma unroll
        for (int i = 0; i < 8; ++i) bs += wpart[i];
        atomicAdd(out, bs * (w * scale));
    }
}

// ---------------------------------------------------------------------------
extern "C" void kernel_launch(void* const* d_in, const int* in_sizes, int n_in,
                              void* d_out, int out_size, void* d_ws, size_t ws_size,
                              hipStream_t stream) {
    const float* X = (const float*)d_in[0];
    const float* Y = (const float*)d_in[1];
    const int total_elems = in_sizes[0];          // G*NPTS*DIM
    const int G = total_elems / (NPTS * DIM);     // 128

    float* out = (float*)d_out;
    hipMemsetAsync(out, 0, sizeof(float) * out_size, stream);

    const float scale = 1.0f / ((float)NPTS * (float)NPTS * (float)G);
    mmd_pipe<<<10 * G, 512, 0, stream>>>(X, Y, out, scale, G);
}

// Round 9
// 114.867 us; speedup vs baseline: 1.7128x; 1.0845x over previous
//
#include <hip/hip_runtime.h>
#include <hip/hip_bf16.h>
#include <stdint.h>
#include <string.h>

typedef __attribute__((ext_vector_type(8))) short short8;   // 8 bf16 (4 VGPRs) MFMA operand
typedef __attribute__((ext_vector_type(4))) float floatx4;  // MFMA accumulator

#define NPTS 256   // points per group
#define DIM  256   // feature dim
#define TILE 128   // output tile per block
#define BK   32    // K-step
#define NIT  (DIM / BK)          // 8 K-iterations

// HW packed fp32->bf16 RNE convert (v_cvt_pk_bf16_f32 on gfx950); also
// accumulates the squared sum of the ROUNDED values (consistent metric).
static __device__ __forceinline__ uint32_t cvtsq2(float a, float b, float& s) {
    __hip_bfloat162 h = __float22bfloat162_rn(float2{a, b});
    uint32_t d;
    memcpy(&d, &h, 4);
    const float lo = __builtin_bit_cast(float, d << 16);
    const float hi = __builtin_bit_cast(float, d & 0xFFFF0000u);
    s += lo * lo + hi * hi;
    return d;
}

// ---------------------------------------------------------------------------
// grid = 10*G linear blocks, XCD-swizzled so all 10 tiles of a group share an
// XCD (L2 reuse). t 0..3 = XY (w=+1), 4..6 = XX upper-tri (w=-0.5/-1/-0.5,
// off-diag tile double-counted via w), 7..9 = YY upper-tri.
//
// LDS: [row][32] linear, 16B-chunk swizzle p = c ^ ((row>>1)&3) on both
// ds_write and ds_read (HW-verified conflict-free: SQ_LDS_BANK_CONFLICT = 0).
//
// Symdiag tiles (t = 4,6,7,9: A panel == B panel) take a fully-separated
// branch that stages ONE panel (half the cvt VALU + loads) and reads both
// MFMA operands from As. Separate loop => no entangled live ranges (the
// round-5 interleaved-conditional version spilled at the 64-VGPR cliff).
//
// Iteration order (both paths): barrier -> ds_read fragments FIRST -> cvt +
// ds_write next slice (hides ds_read latency under staging VALU; compiler
// can't do this reorder itself since As[b^1] vs As[b] aliasing is runtime)
// -> global loads (slice it+2) -> MFMAs.
// ---------------------------------------------------------------------------
__global__ __launch_bounds__(512, 4)
void mmd_pipe(const float* __restrict__ X, const float* __restrict__ Y,
              float* __restrict__ out, float scale, int G) {
    // ---- block -> (group, tile) decode with XCD swizzle ----
    int g, t;
    const int f = blockIdx.x;
    if ((G & 7) == 0) { const int xcd = f & 7, j = f >> 3; g = (j / 10) * 8 + xcd; t = j % 10; }
    else              { g = f / 10; t = f % 10; }

    int ptype, ti, tj; float w;
    if (t < 4)      { ptype = 0; ti = t >> 1; tj = t & 1; w = 1.0f; }
    else if (t < 7) { int u = t - 4; ptype = 1; ti = (u == 2); tj = (u >= 1); w = (u == 1) ? -1.0f : -0.5f; }
    else            { int u = t - 7; ptype = 2; ti = (u == 2); tj = (u >= 1); w = (u == 1) ? -1.0f : -0.5f; }

    const float *Pf, *Qf;
    if (ptype == 0)      { Pf = X; Qf = Y; }
    else if (ptype == 1) { Pf = X; Qf = X; }
    else                 { Pf = Y; Qf = Y; }
    const bool symdiag = (ptype != 0) && (ti == tj);

    const size_t prow0 = (size_t)g * NPTS + (size_t)ti * TILE;
    const size_t qrow0 = (size_t)g * NPTS + (size_t)tj * TILE;

    __shared__ __align__(16) uint16_t As[2][TILE * BK];  // 2 x 8 KB
    __shared__ __align__(16) uint16_t Bs[2][TILE * BK];  // 2 x 8 KB
    __shared__ float rnorm[TILE];
    __shared__ float cnorm[TILE];
    __shared__ float wpart[8];

    const int tid  = threadIdx.x;          // 0..511
    const int lane = tid & 63;
    const int wv   = tid >> 6;             // 0..7
    const int quad = lane >> 4;
    const int l15  = lane & 15;
    const int rowbase = (wv & 3) * 32;     // wave's 32-row stripe
    const int colbase = (wv >> 2) * 64;    // wave's 64-col stripe
    // fragment read: row = base16 + l15 -> (row>>1)&3 == (l15>>1)&3
    const int rsw = (quad ^ ((l15 >> 1) & 3)) * 8;   // swizzled elem offset

    // ---- producer geometry: thread covers row tid>>2, 16B chunk tid&3 ----
    const int prow = tid >> 2;
    const int pchk = tid & 3;
    const float* gA = Pf + (prow0 + prow) * DIM + pchk * 8;
    const int woff = prow * BK + ((pchk ^ ((prow >> 1) & 3)) * 8);  // swizzled

    floatx4 acc[2][4];
    #pragma unroll
    for (int i = 0; i < 2; ++i)
        #pragma unroll
        for (int j = 0; j < 4; ++j) acc[i][j] = (floatx4)0.0f;

    float sqp = 0.0f;                      // this thread's partial row norm (A)

    if (symdiag) {
        // ================= symmetric-diagonal path: B == A =================
        float4 ra0 = *(const float4*)(gA);
        float4 ra1 = *(const float4*)(gA + 4);
        {
            uint4 pa;
            pa.x = cvtsq2(ra0.x, ra0.y, sqp); pa.y = cvtsq2(ra0.z, ra0.w, sqp);
            pa.z = cvtsq2(ra1.x, ra1.y, sqp); pa.w = cvtsq2(ra1.z, ra1.w, sqp);
            *(uint4*)&As[0][woff] = pa;
        }
        ra0 = *(const float4*)(gA + BK);
        ra1 = *(const float4*)(gA + BK + 4);

        #pragma unroll
        for (int it = 0; it < NIT; ++it) {
            const int b = it & 1;
            __syncthreads();

            short8 af[2], bfr[4];
            #pragma unroll
            for (int mi = 0; mi < 2; ++mi)
                af[mi] = *(const short8*)&As[b][(rowbase + mi * 16 + l15) * BK + rsw];
            #pragma unroll
            for (int ni = 0; ni < 4; ++ni)
                bfr[ni] = *(const short8*)&As[b][(colbase + ni * 16 + l15) * BK + rsw];

            if (it < NIT - 1) {
                uint4 pa;
                pa.x = cvtsq2(ra0.x, ra0.y, sqp); pa.y = cvtsq2(ra0.z, ra0.w, sqp);
                pa.z = cvtsq2(ra1.x, ra1.y, sqp); pa.w = cvtsq2(ra1.z, ra1.w, sqp);
                *(uint4*)&As[b ^ 1][woff] = pa;
            }
            if (it < NIT - 2) {
                const int k0 = (it + 2) * BK;
                ra0 = *(const float4*)(gA + k0);
                ra1 = *(const float4*)(gA + k0 + 4);
            }

            #pragma unroll
            for (int mi = 0; mi < 2; ++mi)
                #pragma unroll
                for (int ni = 0; ni < 4; ++ni)
                    acc[mi][ni] = __builtin_amdgcn_mfma_f32_16x16x32_bf16(
                        af[mi], bfr[ni], acc[mi][ni], 0, 0, 0);
        }

        sqp += __shfl_xor(sqp, 1); sqp += __shfl_xor(sqp, 2);
        if ((tid & 3) == 0) rnorm[prow] = sqp;
        __syncthreads();

        float lsum = 0.0f;
        #pragma unroll
        for (int mi = 0; mi < 2; ++mi) {
            #pragma unroll
            for (int i = 0; i < 4; ++i) {
                const int r = rowbase + mi * 16 + quad * 4 + i;
                const float rv = rnorm[r];
                #pragma unroll
                for (int ni = 0; ni < 4; ++ni) {
                    const int c = colbase + ni * 16 + l15;
                    float d2 = rv + rnorm[c] - 2.0f * acc[mi][ni][i];
                    float s = sqrtf(fmaxf(d2, 0.0f));
                    if (r == c) s = 0.0f;
                    lsum += s;
                }
            }
        }
        #pragma unroll
        for (int off = 32; off; off >>= 1) lsum += __shfl_down(lsum, off);
        if (lane == 0) wpart[wv] = lsum;
        __syncthreads();
        if (tid == 0) {
            float bs = 0.0f;
            #pragma unroll
            for (int i = 0; i < 8; ++i) bs += wpart[i];
            atomicAdd(out, bs * (w * scale));
        }
        return;
    }

    // ==================== general path: stage both panels ====================
    const float* gB = Qf + (qrow0 + prow) * DIM + pchk * 8;
    float sqq = 0.0f;

    float4 ra0 = *(const float4*)(gA);
    float4 ra1 = *(const float4*)(gA + 4);
    float4 rb0 = *(const float4*)(gB);
    float4 rb1 = *(const float4*)(gB + 4);
    {
        uint4 pa, pb;
        pa.x = cvtsq2(ra0.x, ra0.y, sqp); pa.y = cvtsq2(ra0.z, ra0.w, sqp);
        pa.z = cvtsq2(ra1.x, ra1.y, sqp); pa.w = cvtsq2(ra1.z, ra1.w, sqp);
        pb.x = cvtsq2(rb0.x, rb0.y, sqq); pb.y = cvtsq2(rb0.z, rb0.w, sqq);
        pb.z = cvtsq2(rb1.x, rb1.y, sqq); pb.w = cvtsq2(rb1.z, rb1.w, sqq);
        *(uint4*)&As[0][woff] = pa;
        *(uint4*)&Bs[0][woff] = pb;
    }
    ra0 = *(const float4*)(gA + BK);
    ra1 = *(const float4*)(gA + BK + 4);
    rb0 = *(const float4*)(gB + BK);
    rb1 = *(const float4*)(gB + BK + 4);

    #pragma unroll
    for (int it = 0; it < NIT; ++it) {
        const int b = it & 1;
        __syncthreads();                    // LDS[b] (written last iter) visible

        // fragments FIRST: ds_read latency hides under the staging VALU below
        short8 af[2], bfr[4];
        #pragma unroll
        for (int mi = 0; mi < 2; ++mi)
            af[mi] = *(const short8*)&As[b][(rowbase + mi * 16 + l15) * BK + rsw];
        #pragma unroll
        for (int ni = 0; ni < 4; ++ni)
            bfr[ni] = *(const short8*)&Bs[b][(colbase + ni * 16 + l15) * BK + rsw];

        if (it < NIT - 1) {                 // write slice it+1 into LDS[b^1]
            uint4 pa, pb;
            pa.x = cvtsq2(ra0.x, ra0.y, sqp); pa.y = cvtsq2(ra0.z, ra0.w, sqp);
            pa.z = cvtsq2(ra1.x, ra1.y, sqp); pa.w = cvtsq2(ra1.z, ra1.w, sqp);
            pb.x = cvtsq2(rb0.x, rb0.y, sqq); pb.y = cvtsq2(rb0.z, rb0.w, sqq);
            pb.z = cvtsq2(rb1.x, rb1.y, sqq); pb.w = cvtsq2(rb1.z, rb1.w, sqq);
            *(uint4*)&As[b ^ 1][woff] = pa;
            *(uint4*)&Bs[b ^ 1][woff] = pb;
        }
        if (it < NIT - 2) {                 // start loading slice it+2
            const int k0 = (it + 2) * BK;
            ra0 = *(const float4*)(gA + k0);
            ra1 = *(const float4*)(gA + k0 + 4);
            rb0 = *(const float4*)(gB + k0);
            rb1 = *(const float4*)(gB + k0 + 4);
        }

        #pragma unroll
        for (int mi = 0; mi < 2; ++mi)
            #pragma unroll
            for (int ni = 0; ni < 4; ++ni)
                acc[mi][ni] = __builtin_amdgcn_mfma_f32_16x16x32_bf16(
                    af[mi], bfr[ni], acc[mi][ni], 0, 0, 0);
    }

    // ---- assemble row/col norms: reduce over the 4 staging threads per row
    sqp += __shfl_xor(sqp, 1); sqp += __shfl_xor(sqp, 2);
    sqq += __shfl_xor(sqq, 1); sqq += __shfl_xor(sqq, 2);
    if ((tid & 3) == 0) { rnorm[prow] = sqp; cnorm[prow] = sqq; }
    __syncthreads();

    // ---- fused epilogue: d = sqrt(max(x2_i + y2_j - 2 S_ij, 0)) ----
    // C/D layout: col = lane&15, row = (lane>>4)*4 + reg.
    float lsum = 0.0f;
    #pragma unroll
    for (int mi = 0; mi < 2; ++mi) {
        #pragma unroll
        for (int i = 0; i < 4; ++i) {
            const int r = rowbase + mi * 16 + quad * 4 + i;
            const float rv = rnorm[r];
            #pragma unroll
            for (int ni = 0; ni < 4; ++ni) {
                const int c = colbase + ni * 16 + l15;
                float d2 = rv + cnorm[c] - 2.0f * acc[mi][ni][i];
                float s = sqrtf(fmaxf(d2, 0.0f));
                lsum += s;
            }
        }
    }
    #pragma unroll
    for (int off = 32; off; off >>= 1) lsum += __shfl_down(lsum, off);
    if (lane == 0) wpart[wv] = lsum;
    __syncthreads();
    if (tid == 0) {
        float bs = 0.0f;
        #pragma unroll
        for (int i = 0; i < 8; ++i) bs += wpart[i];
        atomicAdd(out, bs * (w * scale));
    }
}

// ---------------------------------------------------------------------------
extern "C" void kernel_launch(void* const* d_in, const int* in_sizes, int n_in,
                              void* d_out, int out_size, void* d_ws, size_t ws_size,
                              hipStream_t stream) {
    const float* X = (const float*)d_in[0];
    const float* Y = (const float*)d_in[1];
    const int total_elems = in_sizes[0];          // G*NPTS*DIM
    const int G = total_elems / (NPTS * DIM);     // 128

    float* out = (float*)d_out;
    hipMemsetAsync(out, 0, sizeof(float) * out_size, stream);

    const float scale = 1.0f / ((float)NPTS * (float)NPTS * (float)G);
    mmd_pipe<<<10 * G, 512, 0, stream>>>(X, Y, out, scale, G);
}